// Round 1
// baseline (145.129 us; speedup 1.0000x reference)
//
#include <hip/hip_runtime.h>
#include <math.h>

#define B_TOT 16384
#define H     128
#define NC    10
#define NATT  3
#define TR    16      // rows per block
#define HS    136     // padded LDS row stride in floats (136%32=8 -> 2-way bank alias, free)
#define KT    10      // Taylor terms k=0..9; remainder <= e/10! ~ 7.5e-7
#define EPS   1e-5f

__device__ __forceinline__ float fast_tanh(float a) {
    a = fminf(15.f, fmaxf(-15.f, a));
    float t = __expf(2.f * a);
    return (t - 1.f) / (t + 1.f);
}

extern "C" __global__ __launch_bounds__(256, 2)
void simple_attention_kernel(const float* __restrict__ x,
                             const float* __restrict__ W_in,
                             const float* __restrict__ b_in,
                             const float* __restrict__ W_att,
                             const float* __restrict__ b_att,
                             const float* __restrict__ gamma,
                             const float* __restrict__ beta,
                             const float* __restrict__ W_c,
                             const float* __restrict__ b_c,
                             float* __restrict__ out)
{
    __shared__ __align__(16) float hs[TR * HS];   // h tile
    __shared__ __align__(16) float us[TR * HS];   // x staging, then u tile

    const int tid = threadIdx.x;
    const int rowBase = blockIdx.x * TR;

    // ---- stage x tile into us (coalesced float4) ----
    #pragma unroll
    for (int m = 0; m < 2; ++m) {
        int idx = tid + 256 * m;          // 0..511 ; 32 float4 per row
        int r   = idx >> 5;
        int c4  = idx & 31;
        float4 v = ((const float4*)(x + (size_t)(rowBase + r) * H))[c4];
        *(float4*)&us[r * HS + c4 * 4] = v;
    }
    __syncthreads();

    const int f    = tid & 127;    // output feature
    const int half = tid >> 7;     // 0/1 -> row half
    const int r0   = half * 8;

    // ---- in_proj: h = x @ W_in + b_in ----
    {
        float acc[8] = {0,0,0,0,0,0,0,0};
        for (int k = 0; k < H; k += 4) {
            float w0 = W_in[(k+0)*H + f];
            float w1 = W_in[(k+1)*H + f];
            float w2 = W_in[(k+2)*H + f];
            float w3 = W_in[(k+3)*H + f];
            #pragma unroll
            for (int r = 0; r < 8; ++r) {
                float4 v = *(const float4*)&us[(r0+r)*HS + k];   // wave-uniform addr: LDS broadcast
                acc[r] += v.x*w0 + v.y*w1 + v.z*w2 + v.w*w3;
            }
        }
        float b = b_in[f];
        #pragma unroll
        for (int r = 0; r < 8; ++r) hs[(r0+r)*HS + f] = acc[r] + b;
    }
    __syncthreads();

    const float ck[KT] = {1.f, 1.f, 0.5f, 1.f/6.f, 1.f/24.f, 1.f/120.f,
                          1.f/720.f, 1.f/5040.f, 1.f/40320.f, 1.f/362880.f};

    for (int layer = 0; layer < NATT; ++layer) {
        const float* W = W_att + (size_t)layer * H * H;

        // ---- phase A: u = tanh(h @ W + b_att[layer]) ----
        {
            float acc[8] = {0,0,0,0,0,0,0,0};
            for (int k = 0; k < H; k += 4) {
                float w0 = W[(k+0)*H + f];
                float w1 = W[(k+1)*H + f];
                float w2 = W[(k+2)*H + f];
                float w3 = W[(k+3)*H + f];
                #pragma unroll
                for (int r = 0; r < 8; ++r) {
                    float4 v = *(const float4*)&hs[(r0+r)*HS + k];
                    acc[r] += v.x*w0 + v.y*w1 + v.z*w2 + v.w*w3;
                }
            }
            float b = b_att[layer*H + f];
            #pragma unroll
            for (int r = 0; r < 8; ++r)
                us[(r0+r)*HS + f] = fast_tanh(acc[r] + b);
        }
        __syncthreads();

        // ---- phase B: Taylor-softmax attention + residual + layernorm ----
        {
            const int s = tid & 15;     // 16 threads per row
            const int r = tid >> 4;     // row 0..15
            float hj[8], uj[8], ys[8];
            float S[KT], T[KT];
            #pragma unroll
            for (int k = 0; k < KT; ++k) { S[k] = 0.f; T[k] = 0.f; }

            #pragma unroll
            for (int m = 0; m < 8; ++m) {
                int j = s + 16*m;
                float u = us[r*HS + j];
                float h = hs[r*HS + j];
                uj[m] = u; hj[m] = h;
                float p = 1.f;
                #pragma unroll
                for (int k = 0; k < KT; ++k) {
                    S[k] += p * h;
                    T[k] += p;
                    p *= u;
                }
            }
            // reduce S,T across the 16-thread row group (lanes differ only in s bits)
            #pragma unroll
            for (int k = 0; k < KT; ++k) {
                float sv = S[k], tv = T[k];
                #pragma unroll
                for (int m = 1; m < 16; m <<= 1) {
                    sv += __shfl_xor(sv, m);
                    tv += __shfl_xor(tv, m);
                }
                S[k] = sv * ck[k];
                T[k] = tv * ck[k];
            }
            // out_j = num(u_j)/den(u_j); y = h + out; LN stats
            float lsum = 0.f, lsq = 0.f;
            #pragma unroll
            for (int m = 0; m < 8; ++m) {
                float u = uj[m];
                float num = S[KT-1], den = T[KT-1];
                #pragma unroll
                for (int k = KT-2; k >= 0; --k) {
                    num = num * u + S[k];
                    den = den * u + T[k];
                }
                float y = hj[m] + num / den;
                ys[m] = y;
                lsum += y; lsq += y*y;
            }
            #pragma unroll
            for (int m = 1; m < 16; m <<= 1) {
                lsum += __shfl_xor(lsum, m);
                lsq  += __shfl_xor(lsq,  m);
            }
            float mu  = lsum * (1.f/H);
            float var = lsq  * (1.f/H) - mu*mu;
            float inv = rsqrtf(var + EPS);
            #pragma unroll
            for (int m = 0; m < 8; ++m) {
                int j = s + 16*m;
                float g  = gamma[layer*H + j];
                float be = beta [layer*H + j];
                hs[r*HS + j] = (ys[m] - mu) * inv * g + be;
            }
        }
        __syncthreads();
    }

    // ---- final: out = h @ W_c + b_c  (16 rows x 10 cols = 160 threads) ----
    if (tid < TR * NC) {
        const int r = tid / NC;
        const int c = tid - r * NC;
        float acc = b_c[c];
        for (int k = 0; k < H; ++k)
            acc += hs[r*HS + k] * W_c[k*NC + c];
        out[(size_t)(rowBase + r) * NC + c] = acc;
    }
}

extern "C" void kernel_launch(void* const* d_in, const int* in_sizes, int n_in,
                              void* d_out, int out_size, void* d_ws, size_t ws_size,
                              hipStream_t stream) {
    const float* x     = (const float*)d_in[0];
    const float* W_in  = (const float*)d_in[1];
    const float* b_in  = (const float*)d_in[2];
    const float* W_att = (const float*)d_in[3];
    const float* b_att = (const float*)d_in[4];
    const float* gamma = (const float*)d_in[5];
    const float* beta  = (const float*)d_in[6];
    const float* W_c   = (const float*)d_in[7];
    const float* b_c   = (const float*)d_in[8];
    float* out = (float*)d_out;

    dim3 grid(B_TOT / TR), block(256);
    hipLaunchKernelGGL(simple_attention_kernel, grid, block, 0, stream,
                       x, W_in, b_in, W_att, b_att, gamma, beta, W_c, b_c, out);
}

// Round 2
// 108.678 us; speedup vs baseline: 1.3354x; 1.3354x over previous
//
#include <hip/hip_runtime.h>
#include <math.h>

#define B_TOT 16384
#define H     128
#define NC    10
#define NATT  3
#define TR    16      // rows per block
#define HS    136     // fp32 LDS row stride (544B)
#define HBS   136     // bf16 LDS row stride in ushorts (272B: 16B-aligned, 2-way bank alias = free)
#define KT    8       // Taylor terms; tail <= 2.8e-5
#define EPS   1e-5f

typedef __attribute__((ext_vector_type(8))) short bf16x8;   // 8 bf16 = 4 VGPRs
typedef __attribute__((ext_vector_type(4))) float f32x4;

__device__ __forceinline__ ushort f2bf(float f) {
    union { float f; unsigned u; } v; v.f = f;
    unsigned r = v.u + 0x7fffu + ((v.u >> 16) & 1u);   // RNE
    return (ushort)(r >> 16);
}

__device__ __forceinline__ float fast_tanh(float a) {
    a = fminf(15.f, fmaxf(-15.f, a));
    float t = __expf(2.f * a);
    return (t - 1.f) / (t + 1.f);
}

// ---- prep: Wt[mat][n][k] = W[mat][k][n] as bf16; mat 0 = W_in, 1..3 = W_att ----
extern "C" __global__ __launch_bounds__(256)
void prep_weights(const float* __restrict__ W_in,
                  const float* __restrict__ W_att,
                  ushort* __restrict__ wt)
{
    int i   = blockIdx.x * 256 + threadIdx.x;   // 0..65535
    int mat = i >> 14;
    int idx = i & 16383;
    int k   = idx >> 7;
    int n   = idx & 127;
    float v = (mat == 0) ? W_in[idx] : W_att[(mat - 1) * 16384 + idx];
    wt[mat * 16384 + n * H + k] = f2bf(v);
}

// A[m][k] from LDS (stride HBS), B from global Wt[n][k]; two 16x16 N-tiles per wave
__device__ __forceinline__ void mfma_gemm(const ushort* __restrict__ A,
                                          const ushort* __restrict__ WT,
                                          int col, int quad, int n0,
                                          f32x4& acc0, f32x4& acc1)
{
    acc0 = (f32x4){0.f, 0.f, 0.f, 0.f};
    acc1 = (f32x4){0.f, 0.f, 0.f, 0.f};
    #pragma unroll
    for (int ks = 0; ks < 4; ++ks) {
        const int k0 = ks * 32;
        bf16x8 a  = *(const bf16x8*)&A [col * HBS + k0 + quad * 8];
        bf16x8 b0 = *(const bf16x8*)&WT[(n0      + col) * H + k0 + quad * 8];
        bf16x8 b1 = *(const bf16x8*)&WT[(n0 + 16 + col) * H + k0 + quad * 8];
        acc0 = __builtin_amdgcn_mfma_f32_16x16x32_bf16(a, b0, acc0, 0, 0, 0);
        acc1 = __builtin_amdgcn_mfma_f32_16x16x32_bf16(a, b1, acc1, 0, 0, 0);
    }
}

extern "C" __global__ __launch_bounds__(256, 4)
void simple_attention_kernel(const float* __restrict__ x,
                             const float* __restrict__ b_in,
                             const float* __restrict__ b_att,
                             const float* __restrict__ gamma,
                             const float* __restrict__ beta,
                             const float* __restrict__ W_c,
                             const float* __restrict__ b_c,
                             const ushort* __restrict__ wt,
                             float* __restrict__ out)
{
    __shared__ __align__(16) float  hs[TR * HS];    // h tile fp32
    __shared__ __align__(16) float  us[TR * HS];    // u tile fp32 (aliased as xb bf16 first)
    __shared__ __align__(16) ushort hb[TR * HBS];   // h tile bf16 (MFMA A operand)

    const int tid  = threadIdx.x;
    const int lane = tid & 63;
    const int wave = tid >> 6;
    const int col  = lane & 15;    // MFMA: A row m / C col n-offset
    const int quad = lane >> 4;
    const int n0   = wave * 32;    // this wave's N base (2 tiles of 16)
    const size_t rowBase = (size_t)blockIdx.x * TR;

    // ---- stage x -> bf16 xb (aliases us) ----
    ushort* xb = (ushort*)us;
    #pragma unroll
    for (int m = 0; m < 2; ++m) {
        int idx = tid + 256 * m;          // 0..511 float4s (16 rows x 32)
        int r   = idx >> 5;
        int c4  = idx & 31;
        float4 v = ((const float4*)(x + (rowBase + r) * H))[c4];
        ushort4 b;
        b.x = f2bf(v.x); b.y = f2bf(v.y); b.z = f2bf(v.z); b.w = f2bf(v.w);
        *(ushort4*)&xb[r * HBS + c4 * 4] = b;
    }
    __syncthreads();

    // ---- in_proj: h = x @ W_in + b_in  (MFMA) ----
    {
        f32x4 acc0, acc1;
        mfma_gemm(xb, wt, col, quad, n0, acc0, acc1);
        #pragma unroll
        for (int t = 0; t < 2; ++t) {
            const f32x4 acc = t ? acc1 : acc0;
            const int n = n0 + t * 16 + col;
            const float b = b_in[n];
            #pragma unroll
            for (int r = 0; r < 4; ++r) {
                const int m = quad * 4 + r;
                float hv = acc[r] + b;
                hs[m * HS  + n] = hv;
                hb[m * HBS + n] = f2bf(hv);
            }
        }
    }
    __syncthreads();

    const float ck[KT] = {1.f, 1.f, 0.5f, 1.f/6.f, 1.f/24.f, 1.f/120.f,
                          1.f/720.f, 1.f/5040.f};

    for (int layer = 0; layer < NATT; ++layer) {
        const ushort* WT = wt + (size_t)(1 + layer) * 16384;

        // ---- phase A: u = tanh(h @ W + b_att) (MFMA) ----
        {
            f32x4 acc0, acc1;
            mfma_gemm(hb, WT, col, quad, n0, acc0, acc1);
            #pragma unroll
            for (int t = 0; t < 2; ++t) {
                const f32x4 acc = t ? acc1 : acc0;
                const int n = n0 + t * 16 + col;
                const float b = b_att[layer * H + n];
                #pragma unroll
                for (int r = 0; r < 4; ++r) {
                    const int m = quad * 4 + r;
                    us[m * HS + n] = fast_tanh(acc[r] + b);
                }
            }
        }
        __syncthreads();

        // ---- phase B: Taylor-softmax attention + residual + layernorm ----
        {
            const int s = tid & 15;     // 16 threads per row
            const int r = tid >> 4;     // row 0..15
            float hj[8], uj[8], ys[8];
            float S[KT], T[KT];
            #pragma unroll
            for (int k = 0; k < KT; ++k) { S[k] = 0.f; T[k] = 0.f; }

            #pragma unroll
            for (int m = 0; m < 8; ++m) {
                int j = s + 16 * m;
                float u = us[r * HS + j];
                float h = hs[r * HS + j];
                uj[m] = u; hj[m] = h;
                float p = 1.f;
                #pragma unroll
                for (int k = 0; k < KT; ++k) {
                    S[k] += p * h;
                    T[k] += p;
                    p *= u;
                }
            }
            #pragma unroll
            for (int k = 0; k < KT; ++k) {
                float sv = S[k], tv = T[k];
                #pragma unroll
                for (int m = 1; m < 16; m <<= 1) {
                    sv += __shfl_xor(sv, m);
                    tv += __shfl_xor(tv, m);
                }
                S[k] = sv * ck[k];
                T[k] = tv * ck[k];
            }
            float lsum = 0.f, lsq = 0.f;
            #pragma unroll
            for (int m = 0; m < 8; ++m) {
                float u = uj[m];
                float num = S[KT-1], den = T[KT-1];
                #pragma unroll
                for (int k = KT-2; k >= 0; --k) {
                    num = num * u + S[k];
                    den = den * u + T[k];
                }
                float y = hj[m] + num / den;
                ys[m] = y;
                lsum += y; lsq += y * y;
            }
            #pragma unroll
            for (int m = 1; m < 16; m <<= 1) {
                lsum += __shfl_xor(lsum, m);
                lsq  += __shfl_xor(lsq,  m);
            }
            float mu  = lsum * (1.f / H);
            float var = lsq  * (1.f / H) - mu * mu;
            float inv = rsqrtf(var + EPS);
            #pragma unroll
            for (int m = 0; m < 8; ++m) {
                int j = s + 16 * m;
                float g  = gamma[layer * H + j];
                float be = beta [layer * H + j];
                float hv = (ys[m] - mu) * inv * g + be;
                hs[r * HS  + j] = hv;
                hb[r * HBS + j] = f2bf(hv);
            }
        }
        __syncthreads();
    }

    // ---- final: out = h @ W_c + b_c ----
    if (tid < TR * NC) {
        const int r = tid / NC;
        const int c = tid - r * NC;
        float acc = b_c[c];
        const float4* hv = (const float4*)&hs[r * HS];
        #pragma unroll
        for (int k4 = 0; k4 < 32; ++k4) {
            float4 v = hv[k4];
            acc += v.x * W_c[(k4*4+0)*NC + c] + v.y * W_c[(k4*4+1)*NC + c]
                 + v.z * W_c[(k4*4+2)*NC + c] + v.w * W_c[(k4*4+3)*NC + c];
        }
        out[(rowBase + r) * NC + c] = acc;
    }
}

extern "C" void kernel_launch(void* const* d_in, const int* in_sizes, int n_in,
                              void* d_out, int out_size, void* d_ws, size_t ws_size,
                              hipStream_t stream) {
    const float* x     = (const float*)d_in[0];
    const float* W_in  = (const float*)d_in[1];
    const float* b_in  = (const float*)d_in[2];
    const float* W_att = (const float*)d_in[3];
    const float* b_att = (const float*)d_in[4];
    const float* gamma = (const float*)d_in[5];
    const float* beta  = (const float*)d_in[6];
    const float* W_c   = (const float*)d_in[7];
    const float* b_c   = (const float*)d_in[8];
    float* out  = (float*)d_out;
    ushort* wt  = (ushort*)d_ws;    // 4 * 128 * 128 * 2B = 128 KiB

    hipLaunchKernelGGL(prep_weights, dim3(256), dim3(256), 0, stream,
                       W_in, W_att, wt);
    hipLaunchKernelGGL(simple_attention_kernel, dim3(B_TOT / TR), dim3(256), 0, stream,
                       x, b_in, b_att, gamma, beta, W_c, b_c, wt, out);
}

// Round 3
// 104.414 us; speedup vs baseline: 1.3899x; 1.0408x over previous
//
#include <hip/hip_runtime.h>
#include <math.h>

#define B_TOT 16384
#define H     128
#define NC    10
#define NATT  3
#define TR    16      // rows per block (2 waves, each owns a 64-wide j/n half)
#define HBS   136     // bf16 LDS row stride in ushorts (272B, 16B-aligned)
#define KT    7       // Taylor terms k=0..6; tail <= 2.3e-4
#define EPS   1e-5f

typedef __attribute__((ext_vector_type(8))) short bf16x8;
typedef __attribute__((ext_vector_type(4))) float f32x4;

__device__ __forceinline__ ushort f2bf(float f) {
    union { float f; unsigned u; } v; v.f = f;
    unsigned r = v.u + 0x7fffu + ((v.u >> 16) & 1u);   // RNE
    return (ushort)(r >> 16);
}

__device__ __forceinline__ float fast_tanh(float a) {
    a = fminf(15.f, fmaxf(-15.f, a));
    float t = __expf(2.f * a);
    return (t - 1.f) / (t + 1.f);
}

// v + row_ror<C>(v) : pure VALU (DPP), no LDS pipe
template<int CTRL>
__device__ __forceinline__ float dpp_add(float v) {
    int x = __float_as_int(v);
    int y = __builtin_amdgcn_update_dpp(0, x, CTRL, 0xf, 0xf, false);
    return v + __int_as_float(y);
}
// all-reduce sum across the 16 lanes of a DPP row (our quad-groups are row-aligned)
__device__ __forceinline__ float red16(float v) {
    v = dpp_add<0x121>(v);   // row_ror:1
    v = dpp_add<0x122>(v);   // row_ror:2
    v = dpp_add<0x124>(v);   // row_ror:4
    v = dpp_add<0x128>(v);   // row_ror:8
    return v;
}

// ---- prep: wt[mat][n][k]; mat0=W_in^T, mat1..3=W_att^T, mat4=W_c^T padded to 16 rows ----
extern "C" __global__ __launch_bounds__(256)
void prep_weights(const float* __restrict__ W_in,
                  const float* __restrict__ W_att,
                  const float* __restrict__ W_c,
                  ushort* __restrict__ wt)
{
    int i = blockIdx.x * 256 + threadIdx.x;
    if (i < 65536) {
        int mat = i >> 14, idx = i & 16383;
        int k = idx >> 7, n = idx & 127;
        float v = (mat == 0) ? W_in[idx] : W_att[(mat - 1) * 16384 + idx];
        wt[mat * 16384 + n * H + k] = f2bf(v);
    } else if (i < 65536 + 2048) {
        int idx = i - 65536;
        int n = idx >> 7, k = idx & 127;
        float v = (n < NC) ? W_c[k * NC + n] : 0.f;
        wt[65536 + n * H + k] = f2bf(v);
    }
}

// one wave's GEMM slice: 16 rows x 64 cols (4 tiles), A bf16 from LDS, B from global wt
__device__ __forceinline__ void gemm128(const ushort* __restrict__ ab,
                                        const ushort* __restrict__ wtm,
                                        int s, int q, int wv, f32x4 acc[4])
{
    #pragma unroll
    for (int t = 0; t < 4; ++t) acc[t] = (f32x4){0.f, 0.f, 0.f, 0.f};
    #pragma unroll
    for (int ks = 0; ks < 4; ++ks) {
        bf16x8 a = *(const bf16x8*)&ab[s * HBS + ks * 32 + q * 8];
        #pragma unroll
        for (int t = 0; t < 4; ++t) {
            bf16x8 b = *(const bf16x8*)&wtm[(64 * wv + 16 * t + s) * H + ks * 32 + q * 8];
            acc[t] = __builtin_amdgcn_mfma_f32_16x16x32_bf16(a, b, acc[t], 0, 0, 0);
        }
    }
}

extern "C" __global__ __launch_bounds__(128, 2)
void simple_attention_kernel(const float* __restrict__ x,
                             const float* __restrict__ b_in,
                             const float* __restrict__ b_att,
                             const float* __restrict__ gamma,
                             const float* __restrict__ beta,
                             const float* __restrict__ b_c,
                             const ushort* __restrict__ wt,
                             float* __restrict__ out)
{
    __shared__ __align__(16) ushort ab[TR * HBS];      // bf16 A-tile (h / x)
    __shared__ __align__(16) float  exm[2 * 16 * 20];  // moment exchange (stride 20: 2-way alias only)
    __shared__ __align__(16) float  exl[2 * 16 * 2];   // LN exchange

    const int tid  = threadIdx.x;
    const int wv   = tid >> 6;          // wave 0/1: owns j,n in [64wv, 64wv+64)
    const int lane = tid & 63;
    const int s    = lane & 15;         // A row m / C col offset
    const int q    = lane >> 4;         // quad: C rows 4q..4q+3
    const size_t rowBase = (size_t)blockIdx.x * TR;

    // ---- stage x -> bf16 ab ----
    {
        int row = tid >> 3, seg = tid & 7;
        const float4* src = (const float4*)(x + (rowBase + row) * H + seg * 16);
        ushort* dst = &ab[row * HBS + seg * 16];
        #pragma unroll
        for (int j = 0; j < 4; ++j) {
            float4 v = src[j];
            ushort4 b;
            b.x = f2bf(v.x); b.y = f2bf(v.y); b.z = f2bf(v.z); b.w = f2bf(v.w);
            *(ushort4*)&dst[j * 4] = b;
        }
    }
    __syncthreads();

    float h[4][4];   // h[t][r]: row 4q+r, col 64wv+16t+s

    // ---- in_proj ----
    {
        f32x4 acc[4];
        gemm128(ab, wt, s, q, wv, acc);
        #pragma unroll
        for (int t = 0; t < 4; ++t) {
            float b = b_in[64 * wv + 16 * t + s];
            #pragma unroll
            for (int r = 0; r < 4; ++r) h[t][r] = acc[t][r] + b;
        }
        __syncthreads();   // both waves done reading x from ab
        #pragma unroll
        for (int t = 0; t < 4; ++t) {
            int n = 64 * wv + 16 * t + s;
            #pragma unroll
            for (int r = 0; r < 4; ++r) ab[(4 * q + r) * HBS + n] = f2bf(h[t][r]);
        }
        __syncthreads();
    }

    const float ck[KT] = {1.f, 1.f, 0.5f, 1.f/6.f, 1.f/24.f, 1.f/120.f, 1.f/720.f};

    for (int layer = 0; layer < NATT; ++layer) {
        const ushort* WT = wt + (size_t)(1 + layer) * 16384;

        // ---- phase A: u = tanh(h @ W + b) ----
        f32x4 acc[4];
        gemm128(ab, WT, s, q, wv, acc);
        float u[4][4];
        #pragma unroll
        for (int t = 0; t < 4; ++t) {
            float b = b_att[layer * H + 64 * wv + 16 * t + s];
            #pragma unroll
            for (int r = 0; r < 4; ++r) u[t][r] = fast_tanh(acc[t][r] + b);
        }

        // ---- moments: S_k = sum_j u^k h, T_k = sum_j u^k (k>=1); T0=128 hardcoded ----
        float S[4][KT], T[4][KT - 1];
        #pragma unroll
        for (int r = 0; r < 4; ++r) {
            #pragma unroll
            for (int k = 0; k < KT; ++k) S[r][k] = 0.f;
            #pragma unroll
            for (int k = 0; k < KT - 1; ++k) T[r][k] = 0.f;
        }
        #pragma unroll
        for (int t = 0; t < 4; ++t) {
            #pragma unroll
            for (int r = 0; r < 4; ++r) {
                float uu = u[t][r], hh = h[t][r];
                S[r][0] += hh;
                float p = uu;
                S[r][1] += p * hh; T[r][0] += p;
                #pragma unroll
                for (int k = 2; k < KT; ++k) {
                    p *= uu;
                    S[r][k] += p * hh;
                    T[r][k - 1] += p;
                }
            }
        }
        // intra-wave 16-lane reduce (DPP, VALU pipe) + fold ck
        #pragma unroll
        for (int r = 0; r < 4; ++r) {
            #pragma unroll
            for (int k = 0; k < KT; ++k)     S[r][k] = red16(S[r][k]) * ck[k];
            #pragma unroll
            for (int k = 0; k < KT - 1; ++k) T[r][k] = red16(T[r][k]) * ck[k + 1];
        }
        // cross-wave exchange (one writer lane per quad)
        if (s == 0) {
            #pragma unroll
            for (int r = 0; r < 4; ++r) {
                float* dst = &exm[(wv * 16 + 4 * q + r) * 20];
                *(f32x4*)&dst[0]  = (f32x4){S[r][0], S[r][1], S[r][2], S[r][3]};
                *(f32x4*)&dst[4]  = (f32x4){S[r][4], S[r][5], S[r][6], 0.f};
                *(f32x4*)&dst[8]  = (f32x4){T[r][0], T[r][1], T[r][2], T[r][3]};
                *(f32x4*)&dst[12] = (f32x4){T[r][4], T[r][5], 0.f, 0.f};
            }
        }
        __syncthreads();
        #pragma unroll
        for (int r = 0; r < 4; ++r) {
            const float* src = &exm[((1 - wv) * 16 + 4 * q + r) * 20];
            f32x4 c0 = *(const f32x4*)&src[0];
            f32x4 c1 = *(const f32x4*)&src[4];
            f32x4 c2 = *(const f32x4*)&src[8];
            f32x4 c3 = *(const f32x4*)&src[12];
            S[r][0] += c0.x; S[r][1] += c0.y; S[r][2] += c0.z; S[r][3] += c0.w;
            S[r][4] += c1.x; S[r][5] += c1.y; S[r][6] += c1.z;
            T[r][0] += c2.x; T[r][1] += c2.y; T[r][2] += c2.z; T[r][3] += c2.w;
            T[r][4] += c3.x; T[r][5] += c3.y;
        }

        // ---- Horner: out_j = num(u)/den(u); y = h + out; LN partials ----
        float y[4][4], ls[4] = {0,0,0,0}, lq[4] = {0,0,0,0};
        #pragma unroll
        for (int t = 0; t < 4; ++t) {
            #pragma unroll
            for (int r = 0; r < 4; ++r) {
                float uu = u[t][r];
                float num = S[r][KT - 1];
                #pragma unroll
                for (int k = KT - 2; k >= 0; --k) num = num * uu + S[r][k];
                float den = T[r][KT - 2];
                #pragma unroll
                for (int k = KT - 3; k >= 0; --k) den = den * uu + T[r][k];
                den = den * uu + 128.f;   // c0*T0
                float yy = h[t][r] + num * __builtin_amdgcn_rcpf(den);
                y[t][r] = yy;
                ls[r] += yy; lq[r] += yy * yy;
            }
        }
        #pragma unroll
        for (int r = 0; r < 4; ++r) { ls[r] = red16(ls[r]); lq[r] = red16(lq[r]); }
        if (s == 0) {
            #pragma unroll
            for (int r = 0; r < 4; ++r)
                *(float2*)&exl[(wv * 16 + 4 * q + r) * 2] = make_float2(ls[r], lq[r]);
        }
        __syncthreads();
        float mu[4], inv[4];
        #pragma unroll
        for (int r = 0; r < 4; ++r) {
            float2 o = *(const float2*)&exl[((1 - wv) * 16 + 4 * q + r) * 2];
            float sm = ls[r] + o.x, sq = lq[r] + o.y;
            mu[r] = sm * (1.f / H);
            float var = sq * (1.f / H) - mu[r] * mu[r];
            inv[r] = rsqrtf(var + EPS);
        }
        // ---- epilogue: h = (y-mu)*inv*gamma + beta ; write bf16 to ab ----
        #pragma unroll
        for (int t = 0; t < 4; ++t) {
            int n = 64 * wv + 16 * t + s;
            float g  = gamma[layer * H + n];
            float be = beta [layer * H + n];
            #pragma unroll
            for (int r = 0; r < 4; ++r) {
                float hn = (y[t][r] - mu[r]) * inv[r] * g + be;
                h[t][r] = hn;
                ab[(4 * q + r) * HBS + n] = f2bf(hn);
            }
        }
        __syncthreads();
    }

    // ---- final proj: one MFMA tile on wave 0 (W_c^T padded to 16 rows in wt[mat4]) ----
    if (wv == 0) {
        f32x4 acc = (f32x4){0.f, 0.f, 0.f, 0.f};
        const ushort* WC = wt + 4 * 16384;
        #pragma unroll
        for (int ks = 0; ks < 4; ++ks) {
            bf16x8 a = *(const bf16x8*)&ab[s * HBS + ks * 32 + q * 8];
            bf16x8 b = *(const bf16x8*)&WC[s * H + ks * 32 + q * 8];
            acc = __builtin_amdgcn_mfma_f32_16x16x32_bf16(a, b, acc, 0, 0, 0);
        }
        if (s < NC) {
            float bc = b_c[s];
            #pragma unroll
            for (int r = 0; r < 4; ++r)
                out[(rowBase + 4 * q + r) * NC + s] = acc[r] + bc;
        }
    }
}

extern "C" void kernel_launch(void* const* d_in, const int* in_sizes, int n_in,
                              void* d_out, int out_size, void* d_ws, size_t ws_size,
                              hipStream_t stream) {
    const float* x     = (const float*)d_in[0];
    const float* W_in  = (const float*)d_in[1];
    const float* b_in  = (const float*)d_in[2];
    const float* W_att = (const float*)d_in[3];
    const float* b_att = (const float*)d_in[4];
    const float* gamma = (const float*)d_in[5];
    const float* beta  = (const float*)d_in[6];
    const float* W_c   = (const float*)d_in[7];
    const float* b_c   = (const float*)d_in[8];
    float* out  = (float*)d_out;
    ushort* wt  = (ushort*)d_ws;    // 5 mats: 4*16384 + 2048 ushorts = 136 KiB

    hipLaunchKernelGGL(prep_weights, dim3(264), dim3(256), 0, stream,
                       W_in, W_att, W_c, wt);
    hipLaunchKernelGGL(simple_attention_kernel, dim3(B_TOT / TR), dim3(128), 0, stream,
                       x, b_in, b_att, gamma, beta, b_c, wt, out);
}

// Round 4
// 102.714 us; speedup vs baseline: 1.4129x; 1.0166x over previous
//
#include <hip/hip_runtime.h>
#include <math.h>

#define B_TOT 16384
#define H     128
#define NC    10
#define NATT  3
#define TR    16      // rows per wave; one 64-thread block = one wave, fully independent
#define HBS   136     // bf16 LDS row stride in ushorts (272B, 16B-aligned)
#define KT    5       // degree-4 minimax of exp on [-1,1]; max err ~5.9e-4
#define EPS   1e-5f

typedef __attribute__((ext_vector_type(8))) short bf16x8;
typedef __attribute__((ext_vector_type(4))) float f32x4;

__device__ __forceinline__ ushort f2bf(float f) {
    union { float f; unsigned u; } v; v.f = f;
    unsigned r = v.u + 0x7fffu + ((v.u >> 16) & 1u);   // RNE
    return (ushort)(r >> 16);
}

__device__ __forceinline__ float fast_tanh(float a) {
    a = fminf(15.f, fmaxf(-15.f, a));
    float t = __expf(2.f * a);
    return (t - 1.f) / (t + 1.f);
}

// v + row_ror<C>(v): VALU/DPP, no LDS pipe
template<int CTRL>
__device__ __forceinline__ float dpp_add(float v) {
    int x = __float_as_int(v);
    int y = __builtin_amdgcn_update_dpp(0, x, CTRL, 0xf, 0xf, false);
    return v + __int_as_float(y);
}
// all-reduce sum across a DPP row of 16 lanes (lanes differing in s)
__device__ __forceinline__ float red16(float v) {
    v = dpp_add<0x121>(v);   // row_ror:1
    v = dpp_add<0x122>(v);   // row_ror:2
    v = dpp_add<0x124>(v);   // row_ror:4
    v = dpp_add<0x128>(v);   // row_ror:8
    return v;
}

// ---- prep: wt[mat][n][k]; mat0=W_in^T, mat1..3=W_att^T, mat4=W_c^T padded to 16 rows ----
extern "C" __global__ __launch_bounds__(256)
void prep_weights(const float* __restrict__ W_in,
                  const float* __restrict__ W_att,
                  const float* __restrict__ W_c,
                  ushort* __restrict__ wt)
{
    int i = blockIdx.x * 256 + threadIdx.x;
    if (i < 65536) {
        int mat = i >> 14, idx = i & 16383;
        int k = idx >> 7, n = idx & 127;
        float v = (mat == 0) ? W_in[idx] : W_att[(mat - 1) * 16384 + idx];
        wt[mat * 16384 + n * H + k] = f2bf(v);
    } else if (i < 65536 + 2048) {
        int idx = i - 65536;
        int n = idx >> 7, k = idx & 127;
        float v = (n < NC) ? W_c[k * NC + n] : 0.f;
        wt[65536 + n * H + k] = f2bf(v);
    }
}

extern "C" __global__ __launch_bounds__(64, 1)
void simple_attention_kernel(const float* __restrict__ x,
                             const float* __restrict__ b_in,
                             const float* __restrict__ b_att,
                             const float* __restrict__ gamma,
                             const float* __restrict__ beta,
                             const float* __restrict__ b_c,
                             const ushort* __restrict__ wt,
                             float* __restrict__ out)
{
    __shared__ __align__(16) ushort ab[TR * HBS];   // per-wave bf16 A-tile

    const int lane = threadIdx.x;      // 0..63
    const int s    = lane & 15;        // A row m / C col offset / B col n offset
    const int q    = lane >> 4;        // quad: A k-chunk / C rows 4q..4q+3
    const size_t rowBase = (size_t)blockIdx.x * TR;

    float h[8][4];     // h[t][r]: row 4q+r, col 16t+s  (full 128 cols per wave)
    f32x4 acc[8];

    // ---- in_proj: A direct from x (row s, k = ks*32+q*8), B from wt mat0 ----
    {
        bf16x8 af[4];
        #pragma unroll
        for (int ks = 0; ks < 4; ++ks) {
            const float* xp = x + (rowBase + s) * H + ks * 32 + q * 8;
            float4 v0 = *(const float4*)xp;
            float4 v1 = *(const float4*)(xp + 4);
            bf16x8 a;
            a[0] = f2bf(v0.x); a[1] = f2bf(v0.y); a[2] = f2bf(v0.z); a[3] = f2bf(v0.w);
            a[4] = f2bf(v1.x); a[5] = f2bf(v1.y); a[6] = f2bf(v1.z); a[7] = f2bf(v1.w);
            af[ks] = a;
        }
        #pragma unroll
        for (int t = 0; t < 8; ++t) acc[t] = (f32x4){0.f, 0.f, 0.f, 0.f};
        #pragma unroll
        for (int ks = 0; ks < 4; ++ks) {
            #pragma unroll
            for (int t = 0; t < 8; ++t) {
                bf16x8 b = *(const bf16x8*)&wt[(16 * t + s) * H + ks * 32 + q * 8];
                acc[t] = __builtin_amdgcn_mfma_f32_16x16x32_bf16(af[ks], b, acc[t], 0, 0, 0);
            }
        }
        #pragma unroll
        for (int t = 0; t < 8; ++t) {
            float bi = b_in[16 * t + s];
            #pragma unroll
            for (int r = 0; r < 4; ++r) {
                h[t][r] = acc[t][r] + bi;
                ab[(4 * q + r) * HBS + 16 * t + s] = f2bf(h[t][r]);
            }
        }
    }

    // degree-4 Chebyshev-truncated minimax of e^v on [-1,1]
    const float cm[KT] = {1.00004478f, 0.99730768f, 0.49919676f, 0.17734736f, 0.04379392f};

    #pragma unroll 1
    for (int layer = 0; layer < NATT; ++layer) {
        const ushort* WT = wt + (size_t)(1 + layer) * 16384;

        // ---- phase A: u = tanh(h @ W + b) ; A-frags from per-wave LDS tile ----
        bf16x8 af[4];
        #pragma unroll
        for (int ks = 0; ks < 4; ++ks)
            af[ks] = *(const bf16x8*)&ab[s * HBS + ks * 32 + q * 8];
        #pragma unroll
        for (int t = 0; t < 8; ++t) acc[t] = (f32x4){0.f, 0.f, 0.f, 0.f};
        #pragma unroll
        for (int ks = 0; ks < 4; ++ks) {
            #pragma unroll
            for (int t = 0; t < 8; ++t) {
                bf16x8 b = *(const bf16x8*)&WT[(16 * t + s) * H + ks * 32 + q * 8];
                acc[t] = __builtin_amdgcn_mfma_f32_16x16x32_bf16(af[ks], b, acc[t], 0, 0, 0);
            }
        }
        float u[8][4];
        #pragma unroll
        for (int t = 0; t < 8; ++t) {
            float ba = b_att[layer * H + 16 * t + s];
            #pragma unroll
            for (int r = 0; r < 4; ++r) u[t][r] = fast_tanh(acc[t][r] + ba);
        }

        // ---- raw moments over all 128 cols: S_k = sum u^k h, T_k = sum u^k (k>=1) ----
        float S[4][KT], T[4][KT - 1];
        #pragma unroll
        for (int r = 0; r < 4; ++r) {
            #pragma unroll
            for (int k = 0; k < KT; ++k) S[r][k] = 0.f;
            #pragma unroll
            for (int k = 0; k < KT - 1; ++k) T[r][k] = 0.f;
        }
        #pragma unroll
        for (int t = 0; t < 8; ++t) {
            #pragma unroll
            for (int r = 0; r < 4; ++r) {
                float uu = u[t][r], hh = h[t][r];
                S[r][0] += hh;
                float p = uu;
                S[r][1] += p * hh; T[r][0] += p;
                #pragma unroll
                for (int k = 2; k < KT; ++k) {
                    p *= uu;
                    S[r][k] += p * hh;
                    T[r][k - 1] += p;
                }
            }
        }
        // 16-lane all-reduce (s spans a DPP row) + fold minimax coeffs
        #pragma unroll
        for (int r = 0; r < 4; ++r) {
            #pragma unroll
            for (int k = 0; k < KT; ++k)     S[r][k] = red16(S[r][k]) * cm[k];
            #pragma unroll
            for (int k = 0; k < KT - 1; ++k) T[r][k] = red16(T[r][k]) * cm[k + 1];
        }

        // ---- Horner: out = num(u)/den(u); y = h + out; LN partials ----
        float ls[4] = {0,0,0,0}, lq[4] = {0,0,0,0};
        #pragma unroll
        for (int t = 0; t < 8; ++t) {
            #pragma unroll
            for (int r = 0; r < 4; ++r) {
                float uu = u[t][r];
                float num = S[r][KT - 1];
                #pragma unroll
                for (int k = KT - 2; k >= 0; --k) num = num * uu + S[r][k];
                float den = T[r][KT - 2];
                #pragma unroll
                for (int k = KT - 3; k >= 0; --k) den = den * uu + T[r][k];
                den = den * uu + 128.f * 1.00004478f;   // c0 * T0
                float yy = h[t][r] + num * __builtin_amdgcn_rcpf(den);
                h[t][r] = yy;
                ls[r] += yy; lq[r] += yy * yy;
            }
        }
        #pragma unroll
        for (int r = 0; r < 4; ++r) { ls[r] = red16(ls[r]); lq[r] = red16(lq[r]); }
        float mu[4], inv[4];
        #pragma unroll
        for (int r = 0; r < 4; ++r) {
            mu[r] = ls[r] * (1.f / H);
            float var = lq[r] * (1.f / H) - mu[r] * mu[r];
            inv[r] = rsqrtf(var + EPS);
        }
        // ---- epilogue: h = (y-mu)*inv*gamma + beta ; refresh bf16 A-tile ----
        #pragma unroll
        for (int t = 0; t < 8; ++t) {
            int n = 16 * t + s;
            float g  = gamma[layer * H + n];
            float be = beta [layer * H + n];
            #pragma unroll
            for (int r = 0; r < 4; ++r) {
                float hn = (h[t][r] - mu[r]) * inv[r] * g + be;
                h[t][r] = hn;
                ab[(4 * q + r) * HBS + n] = f2bf(hn);
            }
        }
    }

    // ---- final proj: one MFMA tile; W_c^T padded to 16 rows (wt mat4) ----
    {
        const ushort* WC = wt + 4 * 16384;
        f32x4 facc = (f32x4){0.f, 0.f, 0.f, 0.f};
        #pragma unroll
        for (int ks = 0; ks < 4; ++ks) {
            bf16x8 a = *(const bf16x8*)&ab[s * HBS + ks * 32 + q * 8];
            bf16x8 b = *(const bf16x8*)&WC[s * H + ks * 32 + q * 8];
            facc = __builtin_amdgcn_mfma_f32_16x16x32_bf16(a, b, facc, 0, 0, 0);
        }
        if (s < NC) {
            float bc = b_c[s];
            #pragma unroll
            for (int r = 0; r < 4; ++r)
                out[(rowBase + 4 * q + r) * NC + s] = facc[r] + bc;
        }
    }
}

extern "C" void kernel_launch(void* const* d_in, const int* in_sizes, int n_in,
                              void* d_out, int out_size, void* d_ws, size_t ws_size,
                              hipStream_t stream) {
    const float* x     = (const float*)d_in[0];
    const float* W_in  = (const float*)d_in[1];
    const float* b_in  = (const float*)d_in[2];
    const float* W_att = (const float*)d_in[3];
    const float* b_att = (const float*)d_in[4];
    const float* gamma = (const float*)d_in[5];
    const float* beta  = (const float*)d_in[6];
    const float* W_c   = (const float*)d_in[7];
    const float* b_c   = (const float*)d_in[8];
    float* out  = (float*)d_out;
    ushort* wt  = (ushort*)d_ws;    // 5 mats: 4*16384 + 2048 ushorts = 136 KiB

    hipLaunchKernelGGL(prep_weights, dim3(264), dim3(256), 0, stream,
                       W_in, W_att, W_c, wt);
    hipLaunchKernelGGL(simple_attention_kernel, dim3(B_TOT / TR), dim3(64), 0, stream,
                       x, b_in, b_att, gamma, beta, b_c, wt, out);
}

// Round 5
// 101.804 us; speedup vs baseline: 1.4256x; 1.0089x over previous
//
#include <hip/hip_runtime.h>
#include <math.h>

#define B_TOT 16384
#define H     128
#define NC    10
#define NATT  3
#define TR    16      // rows per block; 2 waves split the 128 cols (64 each)
#define HBS   136     // bf16 LDS row stride in ushorts (272B, 16B-aligned)
#define KT    5       // degree-4 minimax of exp on [-1,1]; max err ~5.9e-4
#define EPS   1e-5f

typedef __attribute__((ext_vector_type(8))) short bf16x8;
typedef __attribute__((ext_vector_type(4))) float f32x4;

__device__ __forceinline__ ushort f2bf(float f) {
    union { float f; unsigned u; } v; v.f = f;
    unsigned r = v.u + 0x7fffu + ((v.u >> 16) & 1u);   // RNE
    return (ushort)(r >> 16);
}

__device__ __forceinline__ float fast_tanh(float a) {
    a = fminf(15.f, fmaxf(-15.f, a));
    float t = __expf(2.f * a);
    return (t - 1.f) / (t + 1.f);
}

template<int CTRL>
__device__ __forceinline__ float dpp_add(float v) {
    int x = __float_as_int(v);
    int y = __builtin_amdgcn_update_dpp(0, x, CTRL, 0xf, 0xf, false);
    return v + __int_as_float(y);
}
// all-reduce over the 16 lanes of a DPP row (lanes differing in s)
__device__ __forceinline__ float red16(float v) {
    v = dpp_add<0x121>(v);   // row_ror:1
    v = dpp_add<0x122>(v);   // row_ror:2
    v = dpp_add<0x124>(v);   // row_ror:4
    v = dpp_add<0x128>(v);   // row_ror:8
    return v;
}

// ---- prep: wt[mat][n][k]; mat0=W_in^T, mat1..3=W_att^T, mat4=W_c^T padded to 16 rows ----
extern "C" __global__ __launch_bounds__(256)
void prep_weights(const float* __restrict__ W_in,
                  const float* __restrict__ W_att,
                  const float* __restrict__ W_c,
                  ushort* __restrict__ wt)
{
    int i = blockIdx.x * 256 + threadIdx.x;
    if (i < 65536) {
        int mat = i >> 14, idx = i & 16383;
        int k = idx >> 7, n = idx & 127;
        float v = (mat == 0) ? W_in[idx] : W_att[(mat - 1) * 16384 + idx];
        wt[mat * 16384 + n * H + k] = f2bf(v);
    } else if (i < 65536 + 2048) {
        int idx = i - 65536;
        int n = idx >> 7, k = idx & 127;
        float v = (n < NC) ? W_c[k * NC + n] : 0.f;
        wt[65536 + n * H + k] = f2bf(v);
    }
}

extern "C" __global__ __launch_bounds__(128, 2)
void simple_attention_kernel(const float* __restrict__ x,
                             const float* __restrict__ b_in,
                             const float* __restrict__ b_att,
                             const float* __restrict__ gamma,
                             const float* __restrict__ beta,
                             const float* __restrict__ b_c,
                             const ushort* __restrict__ wt,
                             float* __restrict__ out)
{
    __shared__ __align__(16) ushort ab[TR * HBS];     // bf16 A-tile (shared by both waves)
    __shared__ __align__(16) float  exm[2 * 16 * 12]; // moment exchange: 9 vals/row, stride 12
    __shared__ __align__(16) float  exl[2 * 16 * 2];  // LN exchange

    const int tid  = threadIdx.x;
    const int wv   = tid >> 6;          // wave 0/1 owns cols [64wv, 64wv+64)
    const int lane = tid & 63;
    const int s    = lane & 15;
    const int q    = lane >> 4;
    const size_t rowBase = (size_t)blockIdx.x * TR;

    float h[4][4];     // h[t][r]: row 4q+r, col 64wv+16t+s
    f32x4 acc[4];

    // ---- in_proj: A direct from x, B from wt mat0; each wave 16x64 ----
    {
        bf16x8 af[4];
        #pragma unroll
        for (int ks = 0; ks < 4; ++ks) {
            const float* xp = x + (rowBase + s) * H + ks * 32 + q * 8;
            float4 v0 = *(const float4*)xp;
            float4 v1 = *(const float4*)(xp + 4);
            bf16x8 a;
            a[0] = f2bf(v0.x); a[1] = f2bf(v0.y); a[2] = f2bf(v0.z); a[3] = f2bf(v0.w);
            a[4] = f2bf(v1.x); a[5] = f2bf(v1.y); a[6] = f2bf(v1.z); a[7] = f2bf(v1.w);
            af[ks] = a;
        }
        #pragma unroll
        for (int t = 0; t < 4; ++t) acc[t] = (f32x4){0.f, 0.f, 0.f, 0.f};
        #pragma unroll
        for (int ks = 0; ks < 4; ++ks) {
            #pragma unroll
            for (int t = 0; t < 4; ++t) {
                bf16x8 b = *(const bf16x8*)&wt[(64 * wv + 16 * t + s) * H + ks * 32 + q * 8];
                acc[t] = __builtin_amdgcn_mfma_f32_16x16x32_bf16(af[ks], b, acc[t], 0, 0, 0);
            }
        }
        #pragma unroll
        for (int t = 0; t < 4; ++t) {
            int n = 64 * wv + 16 * t + s;
            float bi = b_in[n];
            #pragma unroll
            for (int r = 0; r < 4; ++r) {
                h[t][r] = acc[t][r] + bi;
                ab[(4 * q + r) * HBS + n] = f2bf(h[t][r]);
            }
        }
        __syncthreads();
    }

    // degree-4 Chebyshev-truncated minimax of e^v on [-1,1]
    const float cm[KT] = {1.00004478f, 0.99730768f, 0.49919676f, 0.17734736f, 0.04379392f};

    #pragma unroll 1
    for (int layer = 0; layer < NATT; ++layer) {
        const ushort* WT = wt + (size_t)(1 + layer) * 16384;

        // ---- phase A: u = tanh(h @ W + b); A-frags from shared bf16 tile ----
        bf16x8 af[4];
        #pragma unroll
        for (int ks = 0; ks < 4; ++ks)
            af[ks] = *(const bf16x8*)&ab[s * HBS + ks * 32 + q * 8];
        #pragma unroll
        for (int t = 0; t < 4; ++t) acc[t] = (f32x4){0.f, 0.f, 0.f, 0.f};
        #pragma unroll
        for (int ks = 0; ks < 4; ++ks) {
            #pragma unroll
            for (int t = 0; t < 4; ++t) {
                bf16x8 b = *(const bf16x8*)&WT[(64 * wv + 16 * t + s) * H + ks * 32 + q * 8];
                acc[t] = __builtin_amdgcn_mfma_f32_16x16x32_bf16(af[ks], b, acc[t], 0, 0, 0);
            }
        }
        float u[4][4];
        #pragma unroll
        for (int t = 0; t < 4; ++t) {
            float ba = b_att[layer * H + 64 * wv + 16 * t + s];
            #pragma unroll
            for (int r = 0; r < 4; ++r) u[t][r] = fast_tanh(acc[t][r] + ba);
        }

        // ---- partial raw moments over this wave's 64 cols ----
        float S[4][KT], T[4][KT - 1];
        #pragma unroll
        for (int r = 0; r < 4; ++r) {
            #pragma unroll
            for (int k = 0; k < KT; ++k) S[r][k] = 0.f;
            #pragma unroll
            for (int k = 0; k < KT - 1; ++k) T[r][k] = 0.f;
        }
        #pragma unroll
        for (int t = 0; t < 4; ++t) {
            #pragma unroll
            for (int r = 0; r < 4; ++r) {
                float uu = u[t][r], hh = h[t][r];
                S[r][0] += hh;
                float p = uu;
                S[r][1] += p * hh; T[r][0] += p;
                #pragma unroll
                for (int k = 2; k < KT; ++k) {
                    p *= uu;
                    S[r][k] += p * hh;
                    T[r][k - 1] += p;
                }
            }
        }
        #pragma unroll
        for (int r = 0; r < 4; ++r) {
            #pragma unroll
            for (int k = 0; k < KT; ++k)     S[r][k] = red16(S[r][k]);
            #pragma unroll
            for (int k = 0; k < KT - 1; ++k) T[r][k] = red16(T[r][k]);
        }
        // cross-wave moment exchange: s==0 lane of each quad writes rows 4q..4q+3
        if (s == 0) {
            #pragma unroll
            for (int r = 0; r < 4; ++r) {
                float* dst = &exm[(wv * 16 + 4 * q + r) * 12];
                *(f32x4*)&dst[0] = (f32x4){S[r][0], S[r][1], S[r][2], S[r][3]};
                *(f32x4*)&dst[4] = (f32x4){S[r][4], T[r][0], T[r][1], T[r][2]};
                dst[8] = T[r][3];
            }
        }
        __syncthreads();
        #pragma unroll
        for (int r = 0; r < 4; ++r) {
            const float* src = &exm[((1 - wv) * 16 + 4 * q + r) * 12];
            f32x4 c0 = *(const f32x4*)&src[0];
            f32x4 c1 = *(const f32x4*)&src[4];
            float c2 = src[8];
            S[r][0] = (S[r][0] + c0.x) * cm[0];
            S[r][1] = (S[r][1] + c0.y) * cm[1];
            S[r][2] = (S[r][2] + c0.z) * cm[2];
            S[r][3] = (S[r][3] + c0.w) * cm[3];
            S[r][4] = (S[r][4] + c1.x) * cm[4];
            T[r][0] = (T[r][0] + c1.y) * cm[1];
            T[r][1] = (T[r][1] + c1.z) * cm[2];
            T[r][2] = (T[r][2] + c1.w) * cm[3];
            T[r][3] = (T[r][3] + c2)   * cm[4];
        }

        // ---- Horner + residual + LN partials (own 64 cols) ----
        float ls[4] = {0,0,0,0}, lq[4] = {0,0,0,0};
        #pragma unroll
        for (int t = 0; t < 4; ++t) {
            #pragma unroll
            for (int r = 0; r < 4; ++r) {
                float uu = u[t][r];
                float num = S[r][KT - 1];
                #pragma unroll
                for (int k = KT - 2; k >= 0; --k) num = num * uu + S[r][k];
                float den = T[r][KT - 2];
                #pragma unroll
                for (int k = KT - 3; k >= 0; --k) den = den * uu + T[r][k];
                den = den * uu + 128.f * 1.00004478f;   // c0 * T0
                float yy = h[t][r] + num * __builtin_amdgcn_rcpf(den);
                h[t][r] = yy;
                ls[r] += yy; lq[r] += yy * yy;
            }
        }
        #pragma unroll
        for (int r = 0; r < 4; ++r) { ls[r] = red16(ls[r]); lq[r] = red16(lq[r]); }
        if (s == 0) {
            #pragma unroll
            for (int r = 0; r < 4; ++r)
                *(float2*)&exl[(wv * 16 + 4 * q + r) * 2] = make_float2(ls[r], lq[r]);
        }
        __syncthreads();
        float mu[4], inv[4];
        #pragma unroll
        for (int r = 0; r < 4; ++r) {
            float2 o = *(const float2*)&exl[((1 - wv) * 16 + 4 * q + r) * 2];
            float sm = ls[r] + o.x, sq = lq[r] + o.y;
            mu[r] = sm * (1.f / H);
            float var = sq * (1.f / H) - mu[r] * mu[r];
            inv[r] = rsqrtf(var + EPS);
        }
        // ---- epilogue: h = (y-mu)*inv*gamma + beta ; refresh shared bf16 tile ----
        #pragma unroll
        for (int t = 0; t < 4; ++t) {
            int n = 64 * wv + 16 * t + s;
            float g  = gamma[layer * H + n];
            float be = beta [layer * H + n];
            #pragma unroll
            for (int r = 0; r < 4; ++r) {
                float hn = (h[t][r] - mu[r]) * inv[r] * g + be;
                h[t][r] = hn;
                ab[(4 * q + r) * HBS + n] = f2bf(hn);
            }
        }
        __syncthreads();
    }

    // ---- final proj: wave 0 computes 16 rows x NC via one MFMA tile ----
    if (wv == 0) {
        const ushort* WC = wt + 4 * 16384;
        f32x4 facc = (f32x4){0.f, 0.f, 0.f, 0.f};
        #pragma unroll
        for (int ks = 0; ks < 4; ++ks) {
            bf16x8 a = *(const bf16x8*)&ab[s * HBS + ks * 32 + q * 8];
            bf16x8 b = *(const bf16x8*)&WC[s * H + ks * 32 + q * 8];
            facc = __builtin_amdgcn_mfma_f32_16x16x32_bf16(a, b, facc, 0, 0, 0);
        }
        if (s < NC) {
            float bc = b_c[s];
            #pragma unroll
            for (int r = 0; r < 4; ++r)
                out[(rowBase + 4 * q + r) * NC + s] = facc[r] + bc;
        }
    }
}

extern "C" void kernel_launch(void* const* d_in, const int* in_sizes, int n_in,
                              void* d_out, int out_size, void* d_ws, size_t ws_size,
                              hipStream_t stream) {
    const float* x     = (const float*)d_in[0];
    const float* W_in  = (const float*)d_in[1];
    const float* b_in  = (const float*)d_in[2];
    const float* W_att = (const float*)d_in[3];
    const float* b_att = (const float*)d_in[4];
    const float* gamma = (const float*)d_in[5];
    const float* beta  = (const float*)d_in[6];
    const float* W_c   = (const float*)d_in[7];
    const float* b_c   = (const float*)d_in[8];
    float* out  = (float*)d_out;
    ushort* wt  = (ushort*)d_ws;    // 5 mats: 4*16384 + 2048 ushorts = 136 KiB

    hipLaunchKernelGGL(prep_weights, dim3(264), dim3(256), 0, stream,
                       W_in, W_att, W_c, wt);
    hipLaunchKernelGGL(simple_attention_kernel, dim3(B_TOT / TR), dim3(128), 0, stream,
                       x, b_in, b_att, gamma, beta, b_c, wt, out);
}